// Round 10
// baseline (38.911 us; speedup 1.0000x reference)
//
#include <hip/hip_runtime.h>
#include <stdint.h>

#define NQ 900
#define TOPK_PRE 100
#define TOPK_POST 20
#define IOU_THR 0.7f
#define THREADS 512

typedef unsigned long long u64;

__device__ __forceinline__ u64 umin64(u64 a, u64 b) { return a < b ? a : b; }
__device__ __forceinline__ u64 umax64(u64 a, u64 b) { return a > b ? a : b; }

__device__ __forceinline__ void ce(u64& v, int j, bool up, int lane) {
    u64 part = __shfl_xor(v, j);
    bool lower = ((lane & j) == 0);
    v = (up == lower) ? umin64(v, part) : umax64(v, part);
}

// merge two sorted-ascending 128-lists (in LDS) -> sorted ascending top-128 in (c0,c1)
__device__ __forceinline__ void merge_lds(const u64* __restrict__ A,
                                          const u64* __restrict__ B,
                                          u64& c0, u64& c1, int lane) {
    c0 = umin64(A[lane],      B[127 - lane]);
    c1 = umin64(A[64 + lane], B[63 - lane]);
    u64 lo = umin64(c0, c1), hi = umax64(c0, c1);   // j = 64 (reg-local)
    c0 = lo; c1 = hi;
#pragma unroll
    for (int j = 32; j > 0; j >>= 1) {
        bool lower = (lane & j) == 0;
        u64 p0 = __shfl_xor(c0, j);
        u64 p1 = __shfl_xor(c1, j);
        c0 = lower ? umin64(c0, p0) : umax64(c0, p0);
        c1 = lower ? umin64(c1, p1) : umax64(c1, p1);
    }
}

// Output layout (float32):
//   sel_s : [0,      20480)   (16,64,20)
//   sel_b : [20480, 102400)   (16,64,20,4)
//   sel_l : [102400,122880)   (16,64,20)
//   vmask : [122880,143360)   (16,64,20)

__global__ __launch_bounds__(THREADS)
void ovnms_kernel(const float* __restrict__ logits,   // (16,1,57600,2)
                  const float* __restrict__ boxes,    // (16,1,57600,4)
                  const float* __restrict__ tsize,    // (16,2) [h,w]
                  const int*   __restrict__ labels,   // (16,64)
                  float* __restrict__ out)
{
#pragma clang fp contract(off)
    const int row  = blockIdx.x;       // b*64 + p
    const int b    = row >> 6;
    const int p    = row & 63;
    const int tid  = threadIdx.x;
    const int lane = tid & 63;
    const int wid  = tid >> 6;         // 0..7

    __shared__ u64 wl[8 * 128];        // per-wave sorted 128-lists
    __shared__ u64 md[4 * 128];
    __shared__ u64 m2[2 * 128];
    __shared__ u64 fin[128];
    __shared__ float4 bslab[NQ];       // this row's raw boxes (prefetched)
    __shared__ float x1s[TOPK_PRE], y1s[TOPK_PRE], x2s[TOPK_PRE], y2s[TOPK_PRE];
    __shared__ float areas[TOPK_PRE], scs[TOPK_PRE];
    __shared__ u64 sup0[TOPK_PRE], sup1[TOPK_PRE];
    __shared__ u64 keep0s, keep1s;

    const size_t brow0 = (size_t)b * 57600 + (size_t)p * NQ;

    // ---- 0. prefetch this row's box slab into LDS (coalesced, overlaps sort) ----
    {
        const float4* bsrc = (const float4*)(boxes + brow0 * 4);
        if (tid < NQ) bslab[tid] = bsrc[tid];
        int t2 = tid + THREADS;
        if (t2 < NQ) bslab[t2] = bsrc[t2];
    }

    // ---- 1. sigmoid scores -> 2 keys per lane ----
    const float* lrow = logits + brow0 * 2;
    u64 c0, c1;
    {
        int q0 = wid * 128 + lane;
        int q1 = q0 + 64;
        u64 k0 = ~0ull, k1 = ~0ull;
        if (q0 < NQ) {
            float x = lrow[q0 * 2 + 1];
            float s = 1.0f / (1.0f + expf(-x));
            k0 = ((u64)(~__float_as_uint(s)) << 32) | (unsigned)q0;
        }
        if (q1 < NQ) {
            float x = lrow[q1 * 2 + 1];
            float s = 1.0f / (1.0f + expf(-x));
            k1 = ((u64)(~__float_as_uint(s)) << 32) | (unsigned)q1;
        }
        c0 = k0; c1 = k1;
    }

    // ---- 2. in-wave bitonic sort of 128 keys ascending ----
#pragma unroll
    for (int k = 2; k <= 64; k <<= 1) {
#pragma unroll
        for (int j = k >> 1; j > 0; j >>= 1) {
            ce(c0, j, (lane & k) == 0, lane);
            ce(c1, j, ((64 + lane) & k) == 0, lane);
        }
    }
    {   // k = 128
        u64 lo = umin64(c0, c1), hi = umax64(c0, c1);
        c0 = lo; c1 = hi;
#pragma unroll
        for (int j = 32; j > 0; j >>= 1) {
            ce(c0, j, true, lane);
            ce(c1, j, true, lane);
        }
    }

    wl[wid * 128 + lane]      = c0;
    wl[wid * 128 + 64 + lane] = c1;
    __syncthreads();

    // ---- 3. merge tree 8 -> 4 -> 2 -> 1 ----
    if (wid < 4) {
        u64 a0, a1;
        merge_lds(&wl[(2 * wid) * 128], &wl[(2 * wid + 1) * 128], a0, a1, lane);
        md[wid * 128 + lane]      = a0;
        md[wid * 128 + 64 + lane] = a1;
    }
    __syncthreads();
    if (wid < 2) {
        u64 a0, a1;
        merge_lds(&md[(2 * wid) * 128], &md[(2 * wid + 1) * 128], a0, a1, lane);
        m2[wid * 128 + lane]      = a0;
        m2[wid * 128 + 64 + lane] = a1;
    }
    __syncthreads();
    if (wid == 0) {
        u64 a0, a1;
        merge_lds(m2, m2 + 128, a0, a1, lane);
        fin[lane]      = a0;
        fin[64 + lane] = a1;
    }
    __syncthreads();

    // ---- 4. gather top-100 boxes from the LDS slab, scale, areas ----
    if (tid < TOPK_PRE) {
        u64 key = fin[tid];
        int q = (int)(key & 0xFFFFFFFFu);
        scs[tid] = __uint_as_float(~(unsigned)(key >> 32));
        float4 bx = bslab[q];
        float cx = bx.x, cy = bx.y, w = bx.z, h = bx.w;
        float ih = tsize[b * 2 + 0];
        float iw = tsize[b * 2 + 1];
        float xa = (cx - 0.5f * w) * iw;
        float ya = (cy - 0.5f * h) * ih;
        float xb = (cx + 0.5f * w) * iw;
        float yb = (cy + 0.5f * h) * ih;
        x1s[tid] = xa; y1s[tid] = ya; x2s[tid] = xb; y2s[tid] = yb;
        areas[tid] = fmaxf(xb - xa, 0.0f) * fmaxf(yb - ya, 0.0f);
    }
    __syncthreads();

    // ---- 5. suppression bit-matrix via ballot (8 waves, stride 8) ----
    {
        const float xj1a = x1s[lane], yj1a = y1s[lane];
        const float xj2a = x2s[lane], yj2a = y2s[lane], aja = areas[lane];
        const int  j2   = lane + 64;
        const bool hv2  = j2 < TOPK_PRE;
        const int  j2c  = hv2 ? j2 : 0;
        const float xj1b = x1s[j2c], yj1b = y1s[j2c];
        const float xj2b = x2s[j2c], yj2b = y2s[j2c], ajb = areas[j2c];

#pragma unroll 4
        for (int i = wid; i < TOPK_PRE; i += 8) {
            float xi1 = x1s[i], yi1 = y1s[i], xi2 = x2s[i], yi2 = y2s[i], ai = areas[i];
            bool b0 = false;
            if (lane < i) {
                float ltx = fmaxf(xi1, xj1a);
                float lty = fmaxf(yi1, yj1a);
                float rbx = fminf(xi2, xj2a);
                float rby = fminf(yi2, yj2a);
                float wx = fmaxf(rbx - ltx, 0.0f);
                float wy = fmaxf(rby - lty, 0.0f);
                float inter = wx * wy;
                float iou = inter / (((ai + aja) - inter) + 1e-7f);
                b0 = iou > IOU_THR;
            }
            u64 m0 = __ballot(b0);
            bool b1 = false;
            if (hv2 && j2 < i) {
                float ltx = fmaxf(xi1, xj1b);
                float lty = fmaxf(yi1, yj1b);
                float rbx = fminf(xi2, xj2b);
                float rby = fminf(yi2, yj2b);
                float wx = fmaxf(rbx - ltx, 0.0f);
                float wy = fmaxf(rby - lty, 0.0f);
                float inter = wx * wy;
                float iou = inter / (((ai + ajb) - inter) + 1e-7f);
                b1 = iou > IOU_THR;
            }
            u64 m1 = __ballot(b1);
            if (lane == 0) { sup0[i] = m0; sup1[i] = m1; }
        }
    }
    __syncthreads();

    // ---- 6. greedy scan with ffs-skip over alive candidates (wave 0) ----
    if (wid == 0) {
        u64 r0a = sup0[lane];
        u64 r1a = sup1[lane];
        const int  j2  = lane + 64;
        const bool hv2 = j2 < TOPK_PRE;
        u64 r0b = hv2 ? sup0[j2] : 0ull;
        u64 r1b = hv2 ? sup1[j2] : 0ull;
        bool alive_a = true;
        bool alive_b = hv2;

        // group 0: candidates 0..63 — iterate only alive ones
        {
            int i = 0;
            for (;;) {
                u64 act = __ballot(alive_a) & (~0ull << i);
                if (!act) break;
                i = __ffsll(act) - 1;
                alive_a = alive_a && !((r0a >> i) & 1ull);
                alive_b = alive_b && !((r0b >> i) & 1ull);
                if (++i >= 64) break;
            }
        }
        // group 1: candidates 64..99 (lanes 0..35 of alive_b)
        {
            int i = 0;
            for (;;) {
                u64 act = __ballot(alive_b) & (~0ull << i);
                if (!act) break;
                int m = __ffsll(act) - 1;
                if (m >= TOPK_PRE - 64) break;
                alive_a = alive_a && !((r1a >> m) & 1ull);
                alive_b = alive_b && !((r1b >> m) & 1ull);
                i = m + 1;
                if (i >= TOPK_PRE - 64) break;
            }
        }
        u64 B0 = __ballot(alive_a);
        u64 B1 = __ballot(alive_b);
        if (lane == 0) { keep0s = B0; keep1s = B1; }
    }
    __syncthreads();

    // ---- 7. write outputs: thread t takes the t-th kept row ----
    if (tid < TOPK_POST) {
        u64 K0 = keep0s, K1 = keep1s;
        int c0n = __popcll(K0);
        int idx = -1;
        if (tid < c0n) {
            u64 x = K0;
            for (int k = 0; k < tid; ++k) x &= x - 1;
            idx = __ffsll(x) - 1;
        } else {
            int t = tid - c0n;
            if (t < __popcll(K1)) {
                u64 x = K1;
                for (int k = 0; k < t; ++k) x &= x - 1;
                idx = 64 + __ffsll(x) - 1;
            }
        }
        size_t o = (size_t)row * TOPK_POST + (size_t)tid;
        float s = 0.0f, xa = 0.0f, ya = 0.0f, xb = 0.0f, yb = 0.0f;
        float lab = -1.0f, m = 0.0f;
        if (idx >= 0) {
            s = scs[idx];
            xa = x1s[idx]; ya = y1s[idx]; xb = x2s[idx]; yb = y2s[idx];
            lab = (float)labels[row];
            m = 1.0f;
        }
        out[o] = s;
        float* ob = out + 20480 + o * 4;
        ob[0] = xa; ob[1] = ya; ob[2] = xb; ob[3] = yb;
        out[102400 + o] = lab;
        out[122880 + o] = m;
    }
}

extern "C" void kernel_launch(void* const* d_in, const int* in_sizes, int n_in,
                              void* d_out, int out_size, void* d_ws, size_t ws_size,
                              hipStream_t stream) {
    const float* logits = (const float*)d_in[0];
    const float* boxes  = (const float*)d_in[1];
    const float* tsize  = (const float*)d_in[2];
    const int*   labels = (const int*)d_in[3];
    float* out = (float*)d_out;

    ovnms_kernel<<<dim3(1024), dim3(THREADS), 0, stream>>>(logits, boxes, tsize, labels, out);
}

// Round 11
// 37.909 us; speedup vs baseline: 1.0264x; 1.0264x over previous
//
#include <hip/hip_runtime.h>
#include <stdint.h>

#define NQ 900
#define TOPK_PRE 100
#define TOPK_POST 20
#define IOU_THR 0.7f
#define THREADS 512

typedef unsigned long long u64;
typedef unsigned int u32;

__device__ __forceinline__ u64 umin64(u64 a, u64 b) { return a < b ? a : b; }
__device__ __forceinline__ u64 umax64(u64 a, u64 b) { return a > b ? a : b; }

__device__ __forceinline__ u32 ce32(u32 v, int j, bool up, int lane) {
    u32 part = __shfl_xor(v, j);
    bool lower = ((lane & j) == 0);
    u32 mn = v < part ? v : part;
    u32 mx = v < part ? part : v;
    return (up == lower) ? mn : mx;
}

__device__ __forceinline__ void ce64(u64& v, int j, bool up, int lane) {
    u64 part = __shfl_xor(v, j);
    bool lower = ((lane & j) == 0);
    v = (up == lower) ? umin64(v, part) : umax64(v, part);
}

// merge two sorted-ascending u32 128-lists in LDS -> top-128 ascending in (c0,c1)
__device__ __forceinline__ void merge_lds32(const u32* __restrict__ A,
                                            const u32* __restrict__ B,
                                            u32& c0, u32& c1, int lane) {
    u32 a0 = A[lane], a1 = A[64 + lane];
    u32 b0 = B[127 - lane], b1 = B[63 - lane];
    c0 = a0 < b0 ? a0 : b0;
    c1 = a1 < b1 ? a1 : b1;
    u32 lo = c0 < c1 ? c0 : c1;
    u32 hi = c0 < c1 ? c1 : c0;
    c0 = lo; c1 = hi;
#pragma unroll
    for (int j = 32; j > 0; j >>= 1) {
        c0 = ce32(c0, j, true, lane);
        c1 = ce32(c1, j, true, lane);
    }
}

// merge two sorted-ascending u64 128-lists in LDS -> top-128 ascending in (c0,c1)
__device__ __forceinline__ void merge_lds64(const u64* __restrict__ A,
                                            const u64* __restrict__ B,
                                            u64& c0, u64& c1, int lane) {
    c0 = umin64(A[lane],      B[127 - lane]);
    c1 = umin64(A[64 + lane], B[63 - lane]);
    u64 lo = umin64(c0, c1), hi = umax64(c0, c1);
    c0 = lo; c1 = hi;
#pragma unroll
    for (int j = 32; j > 0; j >>= 1) {
        ce64(c0, j, true, lane);
        ce64(c1, j, true, lane);
    }
}

// Output layout (float32):
//   sel_s : [0,      20480)   (16,64,20)
//   sel_b : [20480, 102400)   (16,64,20,4)
//   sel_l : [102400,122880)   (16,64,20)
//   vmask : [122880,143360)   (16,64,20)

__global__ __launch_bounds__(THREADS)
void ovnms_kernel(const float* __restrict__ logits,   // (16,1,57600,2)
                  const float* __restrict__ boxes,    // (16,1,57600,4)
                  const float* __restrict__ tsize,    // (16,2) [h,w]
                  const int*   __restrict__ labels,   // (16,64)
                  float* __restrict__ out)
{
#pragma clang fp contract(off)
    const int row  = blockIdx.x;       // b*64 + p
    const int b    = row >> 6;
    const int p    = row & 63;
    const int tid  = threadIdx.x;
    const int lane = tid & 63;
    const int wid  = tid >> 6;         // 0..7

    __shared__ u32 wl32[8 * 128];
    __shared__ u32 md32[4 * 128];
    __shared__ u32 m232[2 * 128];
    __shared__ u32 fin32[128];
    __shared__ float x1s[TOPK_PRE], y1s[TOPK_PRE], x2s[TOPK_PRE], y2s[TOPK_PRE];
    __shared__ float areas[TOPK_PRE], scs[TOPK_PRE];
    __shared__ u64 sup0[TOPK_PRE], sup1[TOPK_PRE];
    __shared__ u64 keep0s, keep1s;
    __shared__ int tieflag;
    // fallback-only buffers (tie in u32 score keys — not hit on this data)
    __shared__ u64 wl64[8 * 128];
    __shared__ u64 md64[4 * 128];
    __shared__ u64 m264[2 * 128];
    __shared__ u64 fin64[128];

    const size_t brow0 = (size_t)b * 57600 + (size_t)p * NQ;

    // ---- 1. sigmoid scores -> 2 u32 keys per lane (kept in o0/o1 for later) ----
    const float* lrow = logits + brow0 * 2;
    const int q0 = wid * 128 + lane;
    const int q1 = q0 + 64;
    u32 o0 = 0xFFFFFFFFu, o1 = 0xFFFFFFFFu;
    if (q0 < NQ) {
        float x = lrow[q0 * 2 + 1];
        float s = 1.0f / (1.0f + expf(-x));
        o0 = ~__float_as_uint(s);
    }
    if (q1 < NQ) {
        float x = lrow[q1 * 2 + 1];
        float s = 1.0f / (1.0f + expf(-x));
        o1 = ~__float_as_uint(s);
    }

    // ---- 2. in-wave bitonic sort of 128 u32 keys ascending ----
    u32 c0 = o0, c1 = o1;
#pragma unroll
    for (int k = 2; k <= 64; k <<= 1) {
#pragma unroll
        for (int j = k >> 1; j > 0; j >>= 1) {
            c0 = ce32(c0, j, (lane & k) == 0, lane);
            c1 = ce32(c1, j, ((64 + lane) & k) == 0, lane);
        }
    }
    {   // k = 128
        u32 lo = c0 < c1 ? c0 : c1;
        u32 hi = c0 < c1 ? c1 : c0;
        c0 = lo; c1 = hi;
#pragma unroll
        for (int j = 32; j > 0; j >>= 1) {
            c0 = ce32(c0, j, true, lane);
            c1 = ce32(c1, j, true, lane);
        }
    }
    wl32[wid * 128 + lane]      = c0;
    wl32[wid * 128 + 64 + lane] = c1;
    __syncthreads();

    // ---- 3. u32 merge tree 8 -> 4 -> 2 -> 1 ----
    if (wid < 4) {
        u32 a0, a1;
        merge_lds32(&wl32[(2 * wid) * 128], &wl32[(2 * wid + 1) * 128], a0, a1, lane);
        md32[wid * 128 + lane]      = a0;
        md32[wid * 128 + 64 + lane] = a1;
    }
    __syncthreads();
    if (wid < 2) {
        u32 a0, a1;
        merge_lds32(&md32[(2 * wid) * 128], &md32[(2 * wid + 1) * 128], a0, a1, lane);
        m232[wid * 128 + lane]      = a0;
        m232[wid * 128 + 64 + lane] = a1;
    }
    if (tid == 0) tieflag = 0;
    __syncthreads();
    if (wid == 0) {
        u32 a0, a1;
        merge_lds32(m232, m232 + 128, a0, a1, lane);
        fin32[lane]      = a0;
        fin32[64 + lane] = a1;
    }
    __syncthreads();

    // ---- 4. tie check on the score keys that matter (ranks 0..100) ----
    if (tid < TOPK_PRE) {
        if (fin32[tid] == fin32[tid + 1]) tieflag = 1;
    }
    __syncthreads();

    // ---- 5. rank recovery + box gather ----
    if (!tieflag) {
        // distinct: exactly 100 keys <= T, rank = binary search position
        const u32 T = fin32[TOPK_PRE - 1];
        const float ih = tsize[b * 2 + 0];
        const float iw = tsize[b * 2 + 1];
#pragma unroll
        for (int t = 0; t < 2; ++t) {
            u32 o = t ? o1 : o0;
            int q = t ? q1 : q0;
            if (o <= T) {
                int r = 0;
#pragma unroll
                for (int s = 64; s > 0; s >>= 1) {
                    int m = r + s;
                    if (m < 128 && fin32[m] <= o) r = m;
                }
                if (r < TOPK_PRE) {
                    scs[r] = __uint_as_float(~o);
                    const float* brow = boxes + (brow0 + (size_t)q) * 4;
                    float cx = brow[0], cy = brow[1], w = brow[2], h = brow[3];
                    float xa = (cx - 0.5f * w) * iw;
                    float ya = (cy - 0.5f * h) * ih;
                    float xb = (cx + 0.5f * w) * iw;
                    float yb = (cy + 0.5f * h) * ih;
                    x1s[r] = xa; y1s[r] = ya; x2s[r] = xb; y2s[r] = yb;
                    areas[r] = fmaxf(xb - xa, 0.0f) * fmaxf(yb - ya, 0.0f);
                }
            }
        }
    } else {
        // fallback: exact u64 path (score, index) — correctness for any input
        u64 k0 = ((u64)o0 << 32) | (unsigned)q0;
        u64 k1 = ((u64)o1 << 32) | (unsigned)q1;
#pragma unroll
        for (int k = 2; k <= 64; k <<= 1) {
#pragma unroll
            for (int j = k >> 1; j > 0; j >>= 1) {
                ce64(k0, j, (lane & k) == 0, lane);
                ce64(k1, j, ((64 + lane) & k) == 0, lane);
            }
        }
        {
            u64 lo = umin64(k0, k1), hi = umax64(k0, k1);
            k0 = lo; k1 = hi;
#pragma unroll
            for (int j = 32; j > 0; j >>= 1) {
                ce64(k0, j, true, lane);
                ce64(k1, j, true, lane);
            }
        }
        wl64[wid * 128 + lane]      = k0;
        wl64[wid * 128 + 64 + lane] = k1;
        __syncthreads();
        if (wid < 4) {
            u64 a0, a1;
            merge_lds64(&wl64[(2 * wid) * 128], &wl64[(2 * wid + 1) * 128], a0, a1, lane);
            md64[wid * 128 + lane]      = a0;
            md64[wid * 128 + 64 + lane] = a1;
        }
        __syncthreads();
        if (wid < 2) {
            u64 a0, a1;
            merge_lds64(&md64[(2 * wid) * 128], &md64[(2 * wid + 1) * 128], a0, a1, lane);
            m264[wid * 128 + lane]      = a0;
            m264[wid * 128 + 64 + lane] = a1;
        }
        __syncthreads();
        if (wid == 0) {
            u64 a0, a1;
            merge_lds64(m264, m264 + 128, a0, a1, lane);
            fin64[lane]      = a0;
            fin64[64 + lane] = a1;
        }
        __syncthreads();
        if (tid < TOPK_PRE) {
            u64 key = fin64[tid];
            int q = (int)(key & 0xFFFFFFFFu);
            scs[tid] = __uint_as_float(~(unsigned)(key >> 32));
            const float* brow = boxes + (brow0 + (size_t)q) * 4;
            float cx = brow[0], cy = brow[1], w = brow[2], h = brow[3];
            float ih = tsize[b * 2 + 0];
            float iw = tsize[b * 2 + 1];
            float xa = (cx - 0.5f * w) * iw;
            float ya = (cy - 0.5f * h) * ih;
            float xb = (cx + 0.5f * w) * iw;
            float yb = (cy + 0.5f * h) * ih;
            x1s[tid] = xa; y1s[tid] = ya; x2s[tid] = xb; y2s[tid] = yb;
            areas[tid] = fmaxf(xb - xa, 0.0f) * fmaxf(yb - ya, 0.0f);
        }
    }
    __syncthreads();

    // ---- 6. suppression bit-matrix via ballot (8 waves, stride 8) ----
    {
        const float xj1a = x1s[lane], yj1a = y1s[lane];
        const float xj2a = x2s[lane], yj2a = y2s[lane], aja = areas[lane];
        const int  j2   = lane + 64;
        const bool hv2  = j2 < TOPK_PRE;
        const int  j2c  = hv2 ? j2 : 0;
        const float xj1b = x1s[j2c], yj1b = y1s[j2c];
        const float xj2b = x2s[j2c], yj2b = y2s[j2c], ajb = areas[j2c];

#pragma unroll 4
        for (int i = wid; i < TOPK_PRE; i += 8) {
            float xi1 = x1s[i], yi1 = y1s[i], xi2 = x2s[i], yi2 = y2s[i], ai = areas[i];
            bool b0 = false;
            if (lane < i) {
                float ltx = fmaxf(xi1, xj1a);
                float lty = fmaxf(yi1, yj1a);
                float rbx = fminf(xi2, xj2a);
                float rby = fminf(yi2, yj2a);
                float wx = fmaxf(rbx - ltx, 0.0f);
                float wy = fmaxf(rby - lty, 0.0f);
                float inter = wx * wy;
                float iou = inter / (((ai + aja) - inter) + 1e-7f);
                b0 = iou > IOU_THR;
            }
            u64 m0 = __ballot(b0);
            bool b1 = false;
            if (hv2 && j2 < i) {
                float ltx = fmaxf(xi1, xj1b);
                float lty = fmaxf(yi1, yj1b);
                float rbx = fminf(xi2, xj2b);
                float rby = fminf(yi2, yj2b);
                float wx = fmaxf(rbx - ltx, 0.0f);
                float wy = fmaxf(rby - lty, 0.0f);
                float inter = wx * wy;
                float iou = inter / (((ai + ajb) - inter) + 1e-7f);
                b1 = iou > IOU_THR;
            }
            u64 m1 = __ballot(b1);
            if (lane == 0) { sup0[i] = m0; sup1[i] = m1; }
        }
    }
    __syncthreads();

    // ---- 7. greedy scan with ffs-skip over alive candidates (wave 0) ----
    if (wid == 0) {
        u64 r0a = sup0[lane];
        u64 r1a = sup1[lane];
        const int  j2  = lane + 64;
        const bool hv2 = j2 < TOPK_PRE;
        u64 r0b = hv2 ? sup0[j2] : 0ull;
        u64 r1b = hv2 ? sup1[j2] : 0ull;
        bool alive_a = true;
        bool alive_b = hv2;

        {
            int i = 0;
            for (;;) {
                u64 act = __ballot(alive_a) & (~0ull << i);
                if (!act) break;
                i = __ffsll(act) - 1;
                alive_a = alive_a && !((r0a >> i) & 1ull);
                alive_b = alive_b && !((r0b >> i) & 1ull);
                if (++i >= 64) break;
            }
        }
        {
            int i = 0;
            for (;;) {
                u64 act = __ballot(alive_b) & (~0ull << i);
                if (!act) break;
                int m = __ffsll(act) - 1;
                if (m >= TOPK_PRE - 64) break;
                alive_a = alive_a && !((r1a >> m) & 1ull);
                alive_b = alive_b && !((r1b >> m) & 1ull);
                i = m + 1;
                if (i >= TOPK_PRE - 64) break;
            }
        }
        u64 B0 = __ballot(alive_a);
        u64 B1 = __ballot(alive_b);
        if (lane == 0) { keep0s = B0; keep1s = B1; }
    }
    __syncthreads();

    // ---- 8. write outputs: thread t takes the t-th kept row ----
    if (tid < TOPK_POST) {
        u64 K0 = keep0s, K1 = keep1s;
        int c0n = __popcll(K0);
        int idx = -1;
        if (tid < c0n) {
            u64 x = K0;
            for (int k = 0; k < tid; ++k) x &= x - 1;
            idx = __ffsll(x) - 1;
        } else {
            int t = tid - c0n;
            if (t < __popcll(K1)) {
                u64 x = K1;
                for (int k = 0; k < t; ++k) x &= x - 1;
                idx = 64 + __ffsll(x) - 1;
            }
        }
        size_t o = (size_t)row * TOPK_POST + (size_t)tid;
        float s = 0.0f, xa = 0.0f, ya = 0.0f, xb = 0.0f, yb = 0.0f;
        float lab = -1.0f, m = 0.0f;
        if (idx >= 0) {
            s = scs[idx];
            xa = x1s[idx]; ya = y1s[idx]; xb = x2s[idx]; yb = y2s[idx];
            lab = (float)labels[row];
            m = 1.0f;
        }
        out[o] = s;
        float* ob = out + 20480 + o * 4;
        ob[0] = xa; ob[1] = ya; ob[2] = xb; ob[3] = yb;
        out[102400 + o] = lab;
        out[122880 + o] = m;
    }
}

extern "C" void kernel_launch(void* const* d_in, const int* in_sizes, int n_in,
                              void* d_out, int out_size, void* d_ws, size_t ws_size,
                              hipStream_t stream) {
    const float* logits = (const float*)d_in[0];
    const float* boxes  = (const float*)d_in[1];
    const float* tsize  = (const float*)d_in[2];
    const int*   labels = (const int*)d_in[3];
    float* out = (float*)d_out;

    ovnms_kernel<<<dim3(1024), dim3(THREADS), 0, stream>>>(logits, boxes, tsize, labels, out);
}